// Round 2
// baseline (205.036 us; speedup 1.0000x reference)
//
#include <hip/hip_runtime.h>
#include <math.h>

#define HW_ (512 * 512)   // 2^18
#define C_ 64
#define K_ 16
#define B_ 8

// Transpose conv_w [K][C] -> wt [C][K] so per-channel weights are 16 contiguous
// floats at a wave-uniform address (scalarizable to s_load in the main kernel).
__global__ __launch_bounds__(256) void transpose_w_kernel(const float* __restrict__ w,
                                                          float* __restrict__ wt) {
    int i = blockIdx.x * blockDim.x + threadIdx.x;  // 0..1023
    if (i < K_ * C_) {
        int k = i >> 6;   // i / 64
        int c = i & 63;   // i % 64
        wt[c * K_ + k] = w[i];
    }
}

// Each thread handles 4 consecutive pixels: float4 x-loads (16B/lane), float4
// unif loads, float4 out stores. FP accumulation order per pixel is unchanged
// vs the R0 passing kernel (ascending c, fmaf chain), so argmax numerics match.
__global__ __launch_bounds__(256, 4) void quantizer_kernel(
    const float* __restrict__ x,        // [B][C][HW]
    const float* __restrict__ wt,       // [C][K] (transposed weights)
    const float* __restrict__ bias,     // [K]
    const float* __restrict__ palette,  // [K][3]
    const float* __restrict__ unif,     // [B*HW][K]
    float* __restrict__ out)            // [B][3][HW]
{
    int t = blockIdx.x * blockDim.x + threadIdx.x;   // 0..524287 (exact cover)
    int p0 = t << 2;                                  // first of 4 consecutive pixels
    int b = p0 >> 18;                                 // p0 / HW_
    int hw = p0 & (HW_ - 1);                          // multiple of 4 -> 16B aligned
    const float* xp = x + (size_t)b * C_ * HW_ + (size_t)hw;

    // ---- logits for 4 pixels: acc[k][j] = bias[k] + sum_c x[c][j] * W[k][c] ----
    float acc[K_][4];
    #pragma unroll
    for (int k = 0; k < K_; ++k) {
        float bk = bias[k];
        acc[k][0] = bk; acc[k][1] = bk; acc[k][2] = bk; acc[k][3] = bk;
    }

    #pragma unroll 8
    for (int c = 0; c < C_; ++c) {
        float4 xv = *reinterpret_cast<const float4*>(xp + (size_t)c * HW_);
        const float* wp = wt + c * K_;   // wave-uniform address
        #pragma unroll
        for (int k = 0; k < K_; ++k) {
            float w = wp[k];
            acc[k][0] = fmaf(xv.x, w, acc[k][0]);
            acc[k][1] = fmaf(xv.y, w, acc[k][1]);
            acc[k][2] = fmaf(xv.z, w, acc[k][2]);
            acc[k][3] = fmaf(xv.w, w, acc[k][3]);
        }
    }

    // ---- per-pixel: log_softmax form + gumbel-max (same fp expr as jax ref) ----
    float cr[4], cg[4], cb[4];
    #pragma unroll
    for (int j = 0; j < 4; ++j) {
        float m = acc[0][j];
        #pragma unroll
        for (int k = 1; k < K_; ++k) m = fmaxf(m, acc[k][j]);
        float s = 0.0f;
        #pragma unroll
        for (int k = 0; k < K_; ++k) s += expf(acc[k][j] - m);
        float ls = logf(s);

        const float4* up4 = reinterpret_cast<const float4*>(unif + ((size_t)p0 + j) * K_);
        float best = -INFINITY;
        int bi = 0;
        #pragma unroll
        for (int q = 0; q < 4; ++q) {
            float4 v = up4[q];
            float uu0 = v.x, uu1 = v.y, uu2 = v.z, uu3 = v.w;
            float g0 = -logf(-logf(uu0 + 1e-20f) + 1e-20f);
            float g1 = -logf(-logf(uu1 + 1e-20f) + 1e-20f);
            float g2 = -logf(-logf(uu2 + 1e-20f) + 1e-20f);
            float g3 = -logf(-logf(uu3 + 1e-20f) + 1e-20f);
            float t0 = (acc[q * 4 + 0][j] - m) - ls + g0;
            float t1 = (acc[q * 4 + 1][j] - m) - ls + g1;
            float t2 = (acc[q * 4 + 2][j] - m) - ls + g2;
            float t3 = (acc[q * 4 + 3][j] - m) - ls + g3;
            if (t0 > best) { best = t0; bi = q * 4 + 0; }
            if (t1 > best) { best = t1; bi = q * 4 + 1; }
            if (t2 > best) { best = t2; bi = q * 4 + 2; }
            if (t3 > best) { best = t3; bi = q * 4 + 3; }
        }
        cr[j] = palette[bi * 3 + 0];
        cg[j] = palette[bi * 3 + 1];
        cb[j] = palette[bi * 3 + 2];
    }

    // ---- output = palette[idx], three float4 plane stores ----
    size_t obase = (size_t)b * 3 * HW_ + (size_t)hw;
    *reinterpret_cast<float4*>(out + obase)               = make_float4(cr[0], cr[1], cr[2], cr[3]);
    *reinterpret_cast<float4*>(out + obase + HW_)         = make_float4(cg[0], cg[1], cg[2], cg[3]);
    *reinterpret_cast<float4*>(out + obase + 2 * HW_)     = make_float4(cb[0], cb[1], cb[2], cb[3]);
}

extern "C" void kernel_launch(void* const* d_in, const int* in_sizes, int n_in,
                              void* d_out, int out_size, void* d_ws, size_t ws_size,
                              hipStream_t stream) {
    const float* x       = (const float*)d_in[0];
    const float* conv_w  = (const float*)d_in[1];
    const float* conv_b  = (const float*)d_in[2];
    const float* palette = (const float*)d_in[3];
    const float* unif    = (const float*)d_in[4];
    float* out = (float*)d_out;
    float* wt  = (float*)d_ws;   // needs K_*C_*4 = 4 KiB scratch

    hipLaunchKernelGGL(transpose_w_kernel, dim3(4), dim3(256), 0, stream, conv_w, wt);

    // B*HW / 4 pixels-per-thread = 524288 threads = 2048 blocks x 256 (exact)
    hipLaunchKernelGGL(quantizer_kernel, dim3(2048), dim3(256), 0, stream,
                       x, wt, conv_b, palette, unif, out);
}

// Round 3
// 187.679 us; speedup vs baseline: 1.0925x; 1.0925x over previous
//
#include <hip/hip_runtime.h>
#include <math.h>

#define HW_ (512 * 512)   // 2^18
#define C_ 64
#define K_ 16
#define B_ 8

// Transpose conv_w [K][C] -> wt [C][K]; per-channel weights become 16
// contiguous floats at a wave-uniform address (scalarizes to s_load).
__global__ __launch_bounds__(256) void transpose_w_kernel(const float* __restrict__ w,
                                                          float* __restrict__ wt) {
    int i = blockIdx.x * blockDim.x + threadIdx.x;  // 0..1023
    if (i < K_ * C_) {
        int k = i >> 6;
        int c = i & 63;
        wt[c * K_ + k] = w[i];
    }
}

// Per-pixel epilogue: log_softmax form + gumbel-max, same fp expression order
// as the jax reference (and as the passing R0 kernel). Register-lean: gumbel
// streamed directly from the float4 unif loads, no u[16] staging.
__device__ __forceinline__ void epilogue(const float* acc, const float4* up4,
                                         const float* __restrict__ palette,
                                         float& cr, float& cg, float& cb) {
    float m = acc[0];
    #pragma unroll
    for (int k = 1; k < K_; ++k) m = fmaxf(m, acc[k]);
    float s = 0.0f;
    #pragma unroll
    for (int k = 0; k < K_; ++k) s += expf(acc[k] - m);
    float ls = logf(s);

    float best = -INFINITY;
    int bi = 0;
    #pragma unroll
    for (int q = 0; q < 4; ++q) {
        float4 v = up4[q];
        float g0 = -logf(-logf(v.x + 1e-20f) + 1e-20f);
        float g1 = -logf(-logf(v.y + 1e-20f) + 1e-20f);
        float g2 = -logf(-logf(v.z + 1e-20f) + 1e-20f);
        float g3 = -logf(-logf(v.w + 1e-20f) + 1e-20f);
        float t0 = (acc[q * 4 + 0] - m) - ls + g0;
        float t1 = (acc[q * 4 + 1] - m) - ls + g1;
        float t2 = (acc[q * 4 + 2] - m) - ls + g2;
        float t3 = (acc[q * 4 + 3] - m) - ls + g3;
        if (t0 > best) { best = t0; bi = q * 4 + 0; }
        if (t1 > best) { best = t1; bi = q * 4 + 1; }
        if (t2 > best) { best = t2; bi = q * 4 + 2; }
        if (t3 > best) { best = t3; bi = q * 4 + 3; }
    }
    cr = palette[bi * 3 + 0];
    cg = palette[bi * 3 + 1];
    cb = palette[bi * 3 + 2];
}

// 2 consecutive pixels per thread: float2 x-loads (512B per wave-load stream
// granularity), acc[2][16] = 32 VGPRs. __launch_bounds__(256,8) caps VGPR at
// 64 so we keep 8 waves/SIMD for latency hiding.
__global__ __launch_bounds__(256, 8) void quantizer_kernel(
    const float* __restrict__ x,        // [B][C][HW]
    const float* __restrict__ wt,       // [C][K]
    const float* __restrict__ bias,     // [K]
    const float* __restrict__ palette,  // [K][3]
    const float* __restrict__ unif,     // [B*HW][K]
    float* __restrict__ out)            // [B][3][HW]
{
    int t = blockIdx.x * blockDim.x + threadIdx.x;   // 0..1048575 (exact cover)
    int p0 = t << 1;                                  // first of 2 consecutive pixels
    int b = p0 >> 18;
    int hw = p0 & (HW_ - 1);                          // even -> 8B aligned
    const float* xp = x + (size_t)b * C_ * HW_ + (size_t)hw;

    float acc0[K_], acc1[K_];
    #pragma unroll
    for (int k = 0; k < K_; ++k) {
        float bk = bias[k];
        acc0[k] = bk;
        acc1[k] = bk;
    }

    // Ascending-c fmaf chain per pixel == R0's passing numerics.
    #pragma unroll 2
    for (int c = 0; c < C_; c += 4) {
        float2 v0 = *reinterpret_cast<const float2*>(xp + (size_t)(c + 0) * HW_);
        float2 v1 = *reinterpret_cast<const float2*>(xp + (size_t)(c + 1) * HW_);
        float2 v2 = *reinterpret_cast<const float2*>(xp + (size_t)(c + 2) * HW_);
        float2 v3 = *reinterpret_cast<const float2*>(xp + (size_t)(c + 3) * HW_);
        const float* wp = wt + c * K_;   // wave-uniform -> s_load
        #pragma unroll
        for (int k = 0; k < K_; ++k) {
            float w0 = wp[k];
            float w1 = wp[K_ + k];
            float w2 = wp[2 * K_ + k];
            float w3 = wp[3 * K_ + k];
            float a0 = acc0[k];
            a0 = fmaf(v0.x, w0, a0);
            a0 = fmaf(v1.x, w1, a0);
            a0 = fmaf(v2.x, w2, a0);
            a0 = fmaf(v3.x, w3, a0);
            acc0[k] = a0;
            float a1 = acc1[k];
            a1 = fmaf(v0.y, w0, a1);
            a1 = fmaf(v1.y, w1, a1);
            a1 = fmaf(v2.y, w2, a1);
            a1 = fmaf(v3.y, w3, a1);
            acc1[k] = a1;
        }
    }

    const float4* u0 = reinterpret_cast<const float4*>(unif + (size_t)p0 * K_);
    float cr0, cg0, cb0, cr1, cg1, cb1;
    epilogue(acc0, u0,     palette, cr0, cg0, cb0);
    epilogue(acc1, u0 + 4, palette, cr1, cg1, cb1);

    size_t obase = (size_t)b * 3 * HW_ + (size_t)hw;
    *reinterpret_cast<float2*>(out + obase)            = make_float2(cr0, cr1);
    *reinterpret_cast<float2*>(out + obase + HW_)      = make_float2(cg0, cg1);
    *reinterpret_cast<float2*>(out + obase + 2 * HW_)  = make_float2(cb0, cb1);
}

extern "C" void kernel_launch(void* const* d_in, const int* in_sizes, int n_in,
                              void* d_out, int out_size, void* d_ws, size_t ws_size,
                              hipStream_t stream) {
    const float* x       = (const float*)d_in[0];
    const float* conv_w  = (const float*)d_in[1];
    const float* conv_b  = (const float*)d_in[2];
    const float* palette = (const float*)d_in[3];
    const float* unif    = (const float*)d_in[4];
    float* out = (float*)d_out;
    float* wt  = (float*)d_ws;   // K_*C_*4 = 4 KiB scratch

    hipLaunchKernelGGL(transpose_w_kernel, dim3(4), dim3(256), 0, stream, conv_w, wt);

    // 2M pixels / 2 per thread = 1048576 threads = 4096 blocks x 256 (exact)
    hipLaunchKernelGGL(quantizer_kernel, dim3(4096), dim3(256), 0, stream,
                       x, wt, conv_b, palette, unif, out);
}

// Round 4
// 149.697 us; speedup vs baseline: 1.3697x; 1.2537x over previous
//
#include <hip/hip_runtime.h>
#include <math.h>

#define HW_ (512 * 512)   // 2^18
#define C_ 64
#define K_ 16
#define B_ 8
#define TOTAL_ (B_ * HW_)

// Transpose conv_w [K][C] -> wt [C][K]; per-channel weights become 16
// contiguous floats at a wave-uniform address (scalarizes to s_load).
__global__ __launch_bounds__(256) void transpose_w_kernel(const float* __restrict__ w,
                                                          float* __restrict__ wt) {
    int i = blockIdx.x * blockDim.x + threadIdx.x;  // 0..1023
    if (i < K_ * C_) {
        int k = i >> 6;
        int c = i & 63;
        wt[c * K_ + k] = w[i];
    }
}

// Per-pixel epilogue: log_softmax form + gumbel-max, same fp expression order
// as the jax reference (byte-identical to the passing R0/R2 kernels).
__device__ __forceinline__ void epilogue(const float* acc, const float4* up4,
                                         const float* __restrict__ palette,
                                         float& cr, float& cg, float& cb) {
    float m = acc[0];
    #pragma unroll
    for (int k = 1; k < K_; ++k) m = fmaxf(m, acc[k]);
    float s = 0.0f;
    #pragma unroll
    for (int k = 0; k < K_; ++k) s += expf(acc[k] - m);
    float ls = logf(s);

    float best = -INFINITY;
    int bi = 0;
    #pragma unroll
    for (int q = 0; q < 4; ++q) {
        float4 v = up4[q];
        float g0 = -logf(-logf(v.x + 1e-20f) + 1e-20f);
        float g1 = -logf(-logf(v.y + 1e-20f) + 1e-20f);
        float g2 = -logf(-logf(v.z + 1e-20f) + 1e-20f);
        float g3 = -logf(-logf(v.w + 1e-20f) + 1e-20f);
        float t0 = (acc[q * 4 + 0] - m) - ls + g0;
        float t1 = (acc[q * 4 + 1] - m) - ls + g1;
        float t2 = (acc[q * 4 + 2] - m) - ls + g2;
        float t3 = (acc[q * 4 + 3] - m) - ls + g3;
        if (t0 > best) { best = t0; bi = q * 4 + 0; }
        if (t1 > best) { best = t1; bi = q * 4 + 1; }
        if (t2 > best) { best = t2; bi = q * 4 + 2; }
        if (t3 > best) { best = t3; bi = q * 4 + 3; }
    }
    cr = palette[bi * 3 + 0];
    cg = palette[bi * 3 + 1];
    cb = palette[bi * 3 + 2];
}

// 1 pixel/thread (R0's mapping: wave = 64 consecutive pixels), explicit
// depth-2 software pipeline on the channel loop: 8 x-loads in flight while
// 128 FMAs execute. Lean registers (~50 VGPR) + forced 8 waves/SIMD.
__global__ __launch_bounds__(256, 8) void quantizer_kernel(
    const float* __restrict__ x,        // [B][C][HW]
    const float* __restrict__ wt,       // [C][K]
    const float* __restrict__ bias,     // [K]
    const float* __restrict__ palette,  // [K][3]
    const float* __restrict__ unif,     // [B*HW][K]
    float* __restrict__ out)            // [B][3][HW]
{
    int tid = blockIdx.x * blockDim.x + threadIdx.x;   // 524288 threads

    #pragma unroll 1
    for (int p = tid; p < TOTAL_; p += 524288) {       // 4 pixel iterations
        int b = p >> 18;
        int hw = p & (HW_ - 1);
        const float* xp = x + (size_t)b * C_ * HW_ + (size_t)hw;

        float acc[K_];
        #pragma unroll
        for (int k = 0; k < K_; ++k) acc[k] = bias[k];

        // prologue: load channels 0..7
        float cur[8], nxt[8];
        #pragma unroll
        for (int i = 0; i < 8; ++i) cur[i] = xp[(size_t)i * HW_];

        // steady state: issue 8 loads for group g+1, then 128 FMAs for group g.
        // Per-(pixel,k) accumulation order is ascending c 0..63 — bitwise
        // identical to the passing R0 chain.
        #pragma unroll 1
        for (int g = 0; g < 8; ++g) {
            int c0 = g * 8;
            if (g < 7) {
                #pragma unroll
                for (int i = 0; i < 8; ++i)
                    nxt[i] = xp[(size_t)(c0 + 8 + i) * HW_];
            }
            const float* wp = wt + c0 * K_;   // wave-uniform -> s_load
            #pragma unroll
            for (int k = 0; k < K_; ++k) {
                float a = acc[k];
                #pragma unroll
                for (int i = 0; i < 8; ++i)
                    a = fmaf(cur[i], wp[i * K_ + k], a);
                acc[k] = a;
            }
            #pragma unroll
            for (int i = 0; i < 8; ++i) cur[i] = nxt[i];
        }

        const float4* up4 = reinterpret_cast<const float4*>(unif + (size_t)p * K_);
        float cr, cg, cb;
        epilogue(acc, up4, palette, cr, cg, cb);

        size_t obase = (size_t)b * 3 * HW_ + (size_t)hw;
        out[obase]                   = cr;
        out[obase + (size_t)HW_]     = cg;
        out[obase + 2 * (size_t)HW_] = cb;
    }
}

extern "C" void kernel_launch(void* const* d_in, const int* in_sizes, int n_in,
                              void* d_out, int out_size, void* d_ws, size_t ws_size,
                              hipStream_t stream) {
    const float* x       = (const float*)d_in[0];
    const float* conv_w  = (const float*)d_in[1];
    const float* conv_b  = (const float*)d_in[2];
    const float* palette = (const float*)d_in[3];
    const float* unif    = (const float*)d_in[4];
    float* out = (float*)d_out;
    float* wt  = (float*)d_ws;   // K_*C_*4 = 4 KiB scratch

    hipLaunchKernelGGL(transpose_w_kernel, dim3(4), dim3(256), 0, stream, conv_w, wt);

    // 2048 blocks x 256 = 524288 threads, 4 pixels each (same mapping as R0)
    hipLaunchKernelGGL(quantizer_kernel, dim3(2048), dim3(256), 0, stream,
                       x, wt, conv_b, palette, unif, out);
}